// Round 29
// baseline (150.982 us; speedup 1.0000x reference)
//
#include <hip/hip_runtime.h>
#include <math.h>

static constexpr int S_LEN  = 4096;
static constexpr int DMODEL = 768;
static constexpr int NHEAD  = 12;
static constexpr int HDIM   = 64;

typedef __attribute__((ext_vector_type(8))) short   bf16x8;
typedef __attribute__((ext_vector_type(4))) float   f32x4;
typedef __attribute__((ext_vector_type(8))) unsigned short us8;

__device__ __forceinline__ unsigned short f2b(float f) {
  union { float f; unsigned int u; } v; v.f = f;
  unsigned int u = v.u;
  return (unsigned short)((u + 0x7fffu + ((u >> 16) & 1u)) >> 16);  // RNE
}

// DPP butterfly reduction within 16-lane groups (pure VALU).
__device__ __forceinline__ float dpp_max16(float x) {
  float y;
  y = __int_as_float(__builtin_amdgcn_mov_dpp(__float_as_int(x), 0xB1, 0xf, 0xf, true)); x = fmaxf(x, y);
  y = __int_as_float(__builtin_amdgcn_mov_dpp(__float_as_int(x), 0x4E, 0xf, 0xf, true)); x = fmaxf(x, y);
  y = __int_as_float(__builtin_amdgcn_mov_dpp(__float_as_int(x), 0x124, 0xf, 0xf, true)); x = fmaxf(x, y);
  y = __int_as_float(__builtin_amdgcn_mov_dpp(__float_as_int(x), 0x128, 0xf, 0xf, true)); x = fmaxf(x, y);
  return x;
}
__device__ __forceinline__ float dpp_sum16(float x) {
  float y;
  y = __int_as_float(__builtin_amdgcn_mov_dpp(__float_as_int(x), 0xB1, 0xf, 0xf, true)); x += y;
  y = __int_as_float(__builtin_amdgcn_mov_dpp(__float_as_int(x), 0x4E, 0xf, 0xf, true)); x += y;
  y = __int_as_float(__builtin_amdgcn_mov_dpp(__float_as_int(x), 0x124, 0xf, 0xf, true)); x += y;
  y = __int_as_float(__builtin_amdgcn_mov_dpp(__float_as_int(x), 0x128, 0xf, 0xf, true)); x += y;
  return x;
}

// ---------------------------------------------------------------------------
// fp32 -> bf16 bulk convert
// ---------------------------------------------------------------------------
__global__ __launch_bounds__(256)
void cvt_f2b_kern(const float* __restrict__ in, unsigned short* __restrict__ out, int n) {
  int i = (blockIdx.x * blockDim.x + threadIdx.x) * 8;
  if (i >= n) return;
  float4 a = *(const float4*)(in + i);
  float4 b = *(const float4*)(in + i + 4);
  ushort4 o0; o0.x = f2b(a.x); o0.y = f2b(a.y); o0.z = f2b(a.z); o0.w = f2b(a.w);
  ushort4 o1; o1.x = f2b(b.x); o1.y = f2b(b.y); o1.z = f2b(b.z); o1.w = f2b(b.w);
  *(ushort4*)(out + i)     = o0;
  *(ushort4*)(out + i + 4) = o1;
}

// 4 weight matrices in one launch (blockIdx.y selects the matrix)
__global__ __launch_bounds__(256)
void cvt_f2b4_kern(const float* __restrict__ s0, const float* __restrict__ s1,
                   const float* __restrict__ s2, const float* __restrict__ s3,
                   unsigned short* __restrict__ d0, unsigned short* __restrict__ d1,
                   unsigned short* __restrict__ d2, unsigned short* __restrict__ d3,
                   int n) {
  const float* s; unsigned short* d;
  switch (blockIdx.y) {
    case 0: s = s0; d = d0; break;
    case 1: s = s1; d = d1; break;
    case 2: s = s2; d = d2; break;
    default: s = s3; d = d3; break;
  }
  int i = (blockIdx.x * blockDim.x + threadIdx.x) * 8;
  if (i >= n) return;
  float4 a = *(const float4*)(s + i);
  float4 b = *(const float4*)(s + i + 4);
  ushort4 o0; o0.x = f2b(a.x); o0.y = f2b(a.y); o0.z = f2b(a.z); o0.w = f2b(a.w);
  ushort4 o1; o1.x = f2b(b.x); o1.y = f2b(b.y); o1.z = f2b(b.z); o1.w = f2b(b.w);
  *(ushort4*)(d + i)     = o0;
  *(ushort4*)(d + i + 4) = o1;
}

// ---------------------------------------------------------------------------
// bf16 transpose: in [S][D] -> out [D][S], 64x64 tiles via LDS.
// ---------------------------------------------------------------------------
__global__ __launch_bounds__(256)
void transpose_bf16(const unsigned short* __restrict__ in, unsigned short* __restrict__ out) {
  __shared__ __align__(16) unsigned short Ts[64][72];
  const int d0 = blockIdx.x * 64, s0 = blockIdx.y * 64;
  const int r = threadIdx.x >> 2, q = threadIdx.x & 3;
#pragma unroll
  for (int hh = 0; hh < 2; ++hh) {
    const int c8 = q + hh * 4;
    us8 v = *(const us8*)(in + (size_t)(s0 + r) * DMODEL + d0 + c8 * 8);
    *(us8*)(&Ts[r][c8 * 8]) = v;
  }
  __syncthreads();
#pragma unroll
  for (int hh = 0; hh < 2; ++hh) {
    const int sq = q + hh * 4;
    __align__(16) unsigned short tmp[8];
#pragma unroll
    for (int j = 0; j < 8; ++j) tmp[j] = Ts[sq * 8 + j][r];
    *(us8*)(out + (size_t)(d0 + r) * S_LEN + s0 + sq * 8) = *(us8*)tmp;
  }
}

// ---------------------------------------------------------------------------
// LDS-staged GEMM body (unchanged from R28 measured build).
// ---------------------------------------------------------------------------
template<int OUT_MODE>
__device__ __forceinline__
void gemm_body(const unsigned short* __restrict__ A, const unsigned short* __restrict__ B,
               const float* __restrict__ bias, void* __restrict__ Cout,
               int M, int N, int K, float scale, int bx, int by,
               unsigned short* As, unsigned short* Bs) {
  const int l  = threadIdx.x & 63;
  const int w  = threadIdx.x >> 6;
  const int wm = (w >> 1) * 32, wn = (w & 1) * 32;
  const int m0 = by * 64;
  const int n0 = bx * 64;
  const int lr = l & 15, lg = l >> 4;
  const int sr = threadIdx.x >> 2, sq = threadIdx.x & 3;

  f32x4 acc[2][2] = {};
  us8 areg[2], breg[2];

#pragma unroll
  for (int p = 0; p < 2; ++p) {
    const int c = sq + p * 4;
    areg[p] = *(const us8*)(A + (size_t)(m0 + sr) * K + c * 8);
    breg[p] = *(const us8*)(B + (size_t)(n0 + sr) * K + c * 8);
  }
#pragma unroll
  for (int p = 0; p < 2; ++p) {
    const int c = sq + p * 4;
    const int slot = ((c ^ (sr & 7)) * 8);
    *(us8*)(&As[sr * 64 + slot]) = areg[p];
    *(us8*)(&Bs[sr * 64 + slot]) = breg[p];
  }
  __syncthreads();

  const int nsteps = K / 64;  // 12
  for (int t = 0; t < nsteps; ++t) {
    const bool more = (t + 1 < nsteps);
    if (more) {
      const int kn = (t + 1) * 64;
#pragma unroll
      for (int p = 0; p < 2; ++p) {
        const int c = sq + p * 4;
        areg[p] = *(const us8*)(A + (size_t)(m0 + sr) * K + kn + c * 8);
        breg[p] = *(const us8*)(B + (size_t)(n0 + sr) * K + kn + c * 8);
      }
    }
#pragma unroll
    for (int kc = 0; kc < 2; ++kc) {
      const int cr = kc * 4 + lg;
      bf16x8 af[2], bfr[2];
#pragma unroll
      for (int mi = 0; mi < 2; ++mi) {
        const int row = wm + mi * 16 + lr;
        af[mi] = *(const bf16x8*)(&As[row * 64 + ((cr ^ (row & 7)) * 8)]);
      }
#pragma unroll
      for (int ni = 0; ni < 2; ++ni) {
        const int row = wn + ni * 16 + lr;
        bfr[ni] = *(const bf16x8*)(&Bs[row * 64 + ((cr ^ (row & 7)) * 8)]);
      }
#pragma unroll
      for (int mi = 0; mi < 2; ++mi)
#pragma unroll
        for (int ni = 0; ni < 2; ++ni)
          acc[mi][ni] = __builtin_amdgcn_mfma_f32_16x16x32_bf16(af[mi], bfr[ni], acc[mi][ni], 0, 0, 0);
    }
    __syncthreads();
    if (more) {
#pragma unroll
      for (int p = 0; p < 2; ++p) {
        const int c = sq + p * 4;
        const int slot = ((c ^ (sr & 7)) * 8);
        *(us8*)(&As[sr * 64 + slot]) = areg[p];
        *(us8*)(&Bs[sr * 64 + slot]) = breg[p];
      }
      __syncthreads();
    }
  }

  const int orow = (l >> 4) * 4;
#pragma unroll
  for (int mi = 0; mi < 2; ++mi)
#pragma unroll
    for (int ni = 0; ni < 2; ++ni) {
      const int col = n0 + wn + ni * 16 + lr;
      float bb = (OUT_MODE == 1) ? bias[col] : 0.f;
#pragma unroll
      for (int r = 0; r < 4; ++r) {
        const int row = m0 + wm + mi * 16 + orow + r;
        float v = acc[mi][ni][r] * scale;
        if (OUT_MODE == 0)
          ((unsigned short*)Cout)[(size_t)row * N + col] = f2b(v);
        else
          ((float*)Cout)[(size_t)row * N + col] = v + bb;
      }
    }
}

// Fused QKV projection: blockIdx.z selects weight/output/scale.
__global__ __launch_bounds__(256)
void gemm_qkv_lds(const unsigned short* __restrict__ X,
                  const unsigned short* __restrict__ Wq, const unsigned short* __restrict__ Wk,
                  const unsigned short* __restrict__ Wv,
                  unsigned short* __restrict__ Qh, unsigned short* __restrict__ Kh,
                  unsigned short* __restrict__ Vh) {
  __shared__ __align__(16) unsigned short As[64 * 64];
  __shared__ __align__(16) unsigned short Bs[64 * 64];
  const unsigned short* B; unsigned short* C; float scale;
  switch (blockIdx.z) {
    case 0:  B = Wq; C = Qh; scale = 0.125f; break;
    case 1:  B = Wk; C = Kh; scale = 1.0f;   break;
    default: B = Wv; C = Vh; scale = 1.0f;   break;
  }
  gemm_body<0>(X, B, nullptr, C, S_LEN, DMODEL, DMODEL, scale,
               blockIdx.x, blockIdx.y, As, Bs);
}

// Single GEMM (final projection, fp32 out + bias)
__global__ __launch_bounds__(256)
void gemm_lds_f32(const unsigned short* __restrict__ A, const unsigned short* __restrict__ B,
                  const float* __restrict__ bias, float* __restrict__ C) {
  __shared__ __align__(16) unsigned short As[64 * 64];
  __shared__ __align__(16) unsigned short Bs[64 * 64];
  gemm_body<1>(A, B, bias, C, S_LEN, DMODEL, DMODEL, 1.0f,
               blockIdx.x, blockIdx.y, As, Bs);
}

// ---------------------------------------------------------------------------
// Flash-style causal attention, QBLK=128 via 8 waves (512 threads).
// Per-wave code identical to R27 (16 q rows/wave); K/V staged once per
// 128 q rows (halves global traffic + barriers per unit work).
// Grid 384 blocks; placement: heaviest 128 blocks at positions 128..255
// (single-block CUs under round-robin), rest paired heavy+light at
// positions j / j+256. Critical path = max single block = 32 iterations.
// Only the final (diagonal) iteration applies the causal mask.
// LDS 64 KB -> 2 blocks/CU (16 waves/CU).
// ---------------------------------------------------------------------------
__global__ __launch_bounds__(512, 2)
void attn_fwd_mfma(const unsigned short* __restrict__ Q, const unsigned short* __restrict__ K,
                   const unsigned short* __restrict__ Vt, unsigned short* __restrict__ O) {
  __shared__ __align__(16) unsigned short Ks[2][64 * 64];
  __shared__ __align__(16) unsigned short Vs[2][64 * 64];
  __shared__ __align__(16) unsigned short Ps[8][2 * 16 * 64];

  // position -> rank (desc weight) mapping
  const int pos = blockIdx.x;
  int rank;
  if (pos < 128)       rank = 128 + pos;          // pairs, heavy side
  else if (pos < 256)  rank = pos - 128;          // singles: heaviest
  else                 rank = 383 - (pos - 256);  // pairs, light side
  const int qtile = 31 - rank / NHEAD;            // 128-row q tile, 0..31
  const int h     = rank % NHEAD;
  const int q0b   = qtile * 128;

  const int tid = threadIdx.x;
  const int w = tid >> 6, l = tid & 63;
  const int lr = l & 15, lg = l >> 4;
  const int sr = tid >> 3, sq = tid & 7;   // staging: 64 rows x 8 chunks

  // Q fragments (scale pre-folded into Q)
  bf16x8 qf[2];
#pragma unroll
  for (int kc = 0; kc < 2; ++kc)
    qf[kc] = *(const bf16x8*)(Q + (size_t)(q0b + w * 16 + lr) * DMODEL + h * HDIM + kc * 32 + lg * 8);

  f32x4 o_acc[4] = {};
  float m_i[4], l_i[4];
#pragma unroll
  for (int r = 0; r < 4; ++r) { m_i[r] = -1e30f; l_i[r] = 0.f; }

  const int nt = qtile + 1;   // 128-kv iterations

  us8 kreg[2], vreg[2];

  // ---- prologue: stage tile 0 ----
#pragma unroll
  for (int hh = 0; hh < 2; ++hh) {
    kreg[hh] = *(const us8*)(K  + (size_t)(hh * 64 + sr) * DMODEL + h * HDIM + sq * 8);
    vreg[hh] = *(const us8*)(Vt + (size_t)(h * HDIM + sr) * S_LEN + hh * 64 + sq * 8);
  }
#pragma unroll
  for (int hh = 0; hh < 2; ++hh) {
    const int sw = (sq * 8) ^ ((sr & 7) * 8);
    *(us8*)(&Ks[hh][sr * 64 + sw]) = kreg[hh];
    *(us8*)(&Vs[hh][sr * 64 + sw]) = vreg[hh];
  }
  __syncthreads();

  for (int t = 0; t < nt; ++t) {
    const int k0 = t * 128;
    const bool more = (t + 1 < nt);
    const bool need_mask = (t == qtile);

    // ---- prefetch next 128-kv tile into registers ----
    if (more) {
      const int k0n = k0 + 128;
#pragma unroll
      for (int hh = 0; hh < 2; ++hh) {
        kreg[hh] = *(const us8*)(K  + (size_t)(k0n + hh * 64 + sr) * DMODEL + h * HDIM + sq * 8);
        vreg[hh] = *(const us8*)(Vt + (size_t)(h * HDIM + sr) * S_LEN + k0n + hh * 64 + sq * 8);
      }
    }

    // ---- S = Q K^T over 128 kv (16 MFMA) ----
    f32x4 sacc[2][4] = {};
#pragma unroll
    for (int hh = 0; hh < 2; ++hh)
#pragma unroll
      for (int kc = 0; kc < 2; ++kc)
#pragma unroll
        for (int cb = 0; cb < 4; ++cb) {
          const int kv = cb * 16 + lr;
          bf16x8 kf = *(const bf16x8*)(&Ks[hh][kv * 64 + ((kc * 32 + lg * 8) ^ ((kv & 7) * 8))]);
          sacc[hh][cb] = __builtin_amdgcn_mfma_f32_16x16x32_bf16(qf[kc], kf, sacc[hh][cb], 0, 0, 0);
        }

    // ---- online softmax (8 elems/row) ----
    float p[4][8];
#pragma unroll
    for (int r = 0; r < 4; ++r) {
      const int qg = q0b + w * 16 + lg * 4 + r;
      float sv[8];
#pragma unroll
      for (int hh = 0; hh < 2; ++hh)
#pragma unroll
        for (int cb = 0; cb < 4; ++cb)
          sv[hh * 4 + cb] = sacc[hh][cb][r];
      if (need_mask) {
#pragma unroll
        for (int hh = 0; hh < 2; ++hh)
#pragma unroll
          for (int cb = 0; cb < 4; ++cb) {
            const int kg = k0 + hh * 64 + cb * 16 + lr;
            if (kg > qg) sv[hh * 4 + cb] = -1e30f;
          }
      }
      float mt = fmaxf(fmaxf(fmaxf(sv[0], sv[1]), fmaxf(sv[2], sv[3])),
                       fmaxf(fmaxf(sv[4], sv[5]), fmaxf(sv[6], sv[7])));
      mt = dpp_max16(mt);
      const float mnew = fmaxf(m_i[r], mt);
      const float alpha = __expf(m_i[r] - mnew);
      m_i[r] = mnew;
      float rs = 0.f;
#pragma unroll
      for (int e = 0; e < 8; ++e) { p[r][e] = __expf(sv[e] - mnew); rs += p[r][e]; }
      rs = dpp_sum16(rs);
      l_i[r] = l_i[r] * alpha + rs;
#pragma unroll
      for (int db = 0; db < 4; ++db) o_acc[db][r] *= alpha;
    }

    // ---- P -> bf16, per-wave LDS re-layout ----
#pragma unroll
    for (int r = 0; r < 4; ++r) {
      const int qloc = lg * 4 + r;
#pragma unroll
      for (int hh = 0; hh < 2; ++hh)
#pragma unroll
        for (int cb = 0; cb < 4; ++cb) {
          const int kvl = cb * 16 + lr;
          Ps[w][hh * 1024 + qloc * 64 + (kvl ^ ((qloc & 7) * 8))] = f2b(p[r][hh * 4 + cb]);
        }
    }

    // ---- O += P V over 128 kv (16 MFMA) ----
#pragma unroll
    for (int hh = 0; hh < 2; ++hh)
#pragma unroll
      for (int kc = 0; kc < 2; ++kc) {
        bf16x8 pf = *(const bf16x8*)(&Ps[w][hh * 1024 + lr * 64 + ((kc * 32 + lg * 8) ^ ((lr & 7) * 8))]);
#pragma unroll
        for (int db = 0; db < 4; ++db) {
          const int d = db * 16 + lr;
          bf16x8 vf = *(const bf16x8*)(&Vs[hh][d * 64 + ((kc * 32 + lg * 8) ^ ((d & 7) * 8))]);
          o_acc[db] = __builtin_amdgcn_mfma_f32_16x16x32_bf16(pf, vf, o_acc[db], 0, 0, 0);
        }
      }

    __syncthreads();   // all reads of Ks/Vs done
    if (more) {
#pragma unroll
      for (int hh = 0; hh < 2; ++hh) {
        const int sw = (sq * 8) ^ ((sr & 7) * 8);
        *(us8*)(&Ks[hh][sr * 64 + sw]) = kreg[hh];
        *(us8*)(&Vs[hh][sr * 64 + sw]) = vreg[hh];
      }
      __syncthreads();   // next tile visible
    }
  }

  // ---- epilogue: normalize, store ctx (bf16) ----
#pragma unroll
  for (int r = 0; r < 4; ++r) {
    const float inv = 1.f / l_i[r];
    const int row = q0b + w * 16 + lg * 4 + r;
#pragma unroll
    for (int db = 0; db < 4; ++db)
      O[(size_t)row * DMODEL + h * HDIM + db * 16 + lr] = f2b(o_acc[db][r] * inv);
  }
}

// ---------------------------------------------------------------------------
extern "C" void kernel_launch(void* const* d_in, const int* in_sizes, int n_in,
                              void* d_out, int out_size, void* d_ws, size_t ws_size,
                              hipStream_t stream) {
  const float* x  = (const float*)d_in[0];
  const float* Wq = (const float*)d_in[1];
  const float* Wk = (const float*)d_in[2];
  const float* Wv = (const float*)d_in[3];
  const float* Wo = (const float*)d_in[4];
  const float* bo = (const float*)d_in[5];
  float* out = (float*)d_out;

  const size_t SD = (size_t)S_LEN * DMODEL;   // 3,145,728
  const size_t DD = (size_t)DMODEL * DMODEL;  //   589,824

  unsigned short* xh   = (unsigned short*)d_ws;
  unsigned short* Wqh  = xh   + SD;
  unsigned short* Wkh  = Wqh  + DD;
  unsigned short* Wvh  = Wkh  + DD;
  unsigned short* Woh  = Wvh  + DD;
  unsigned short* Qh   = Woh  + DD;
  unsigned short* Kh   = Qh   + SD;
  unsigned short* Vh   = Kh   + SD;
  unsigned short* Vth  = Vh   + SD;
  unsigned short* ctxh = Vth  + SD;

  const dim3 blk(256);

  cvt_f2b_kern<<<dim3((int)(SD / 8 / 256)), blk, 0, stream>>>(x, xh, (int)SD);
  cvt_f2b4_kern<<<dim3((int)(DD / 8 / 256), 4), blk, 0, stream>>>(
      Wq, Wk, Wv, Wo, Wqh, Wkh, Wvh, Woh, (int)DD);

  gemm_qkv_lds<<<dim3(DMODEL / 64, S_LEN / 64, 3), blk, 0, stream>>>(
      xh, Wqh, Wkh, Wvh, Qh, Kh, Vh);

  transpose_bf16<<<dim3(DMODEL / 64, S_LEN / 64), blk, 0, stream>>>(Vh, Vth);

  attn_fwd_mfma<<<dim3(S_LEN / 128 * NHEAD), dim3(512), 0, stream>>>(Qh, Kh, Vth, ctxh);

  gemm_lds_f32<<<dim3(DMODEL / 64, S_LEN / 64), blk, 0, stream>>>(ctxh, Woh, bo, out);
}

// Round 30
// 133.545 us; speedup vs baseline: 1.1306x; 1.1306x over previous
//
#include <hip/hip_runtime.h>
#include <math.h>

static constexpr int S_LEN  = 4096;
static constexpr int DMODEL = 768;
static constexpr int NHEAD  = 12;
static constexpr int HDIM   = 64;

typedef __attribute__((ext_vector_type(8))) short   bf16x8;
typedef __attribute__((ext_vector_type(4))) float   f32x4;
typedef __attribute__((ext_vector_type(8))) unsigned short us8;

__device__ __forceinline__ unsigned short f2b(float f) {
  union { float f; unsigned int u; } v; v.f = f;
  unsigned int u = v.u;
  return (unsigned short)((u + 0x7fffu + ((u >> 16) & 1u)) >> 16);  // RNE
}

// DPP butterfly reduction within 16-lane groups (pure VALU).
__device__ __forceinline__ float dpp_max16(float x) {
  float y;
  y = __int_as_float(__builtin_amdgcn_mov_dpp(__float_as_int(x), 0xB1, 0xf, 0xf, true)); x = fmaxf(x, y);
  y = __int_as_float(__builtin_amdgcn_mov_dpp(__float_as_int(x), 0x4E, 0xf, 0xf, true)); x = fmaxf(x, y);
  y = __int_as_float(__builtin_amdgcn_mov_dpp(__float_as_int(x), 0x124, 0xf, 0xf, true)); x = fmaxf(x, y);
  y = __int_as_float(__builtin_amdgcn_mov_dpp(__float_as_int(x), 0x128, 0xf, 0xf, true)); x = fmaxf(x, y);
  return x;
}
__device__ __forceinline__ float dpp_sum16(float x) {
  float y;
  y = __int_as_float(__builtin_amdgcn_mov_dpp(__float_as_int(x), 0xB1, 0xf, 0xf, true)); x += y;
  y = __int_as_float(__builtin_amdgcn_mov_dpp(__float_as_int(x), 0x4E, 0xf, 0xf, true)); x += y;
  y = __int_as_float(__builtin_amdgcn_mov_dpp(__float_as_int(x), 0x124, 0xf, 0xf, true)); x += y;
  y = __int_as_float(__builtin_amdgcn_mov_dpp(__float_as_int(x), 0x128, 0xf, 0xf, true)); x += y;
  return x;
}

// ---------------------------------------------------------------------------
// fp32 -> bf16 bulk convert
// ---------------------------------------------------------------------------
__global__ __launch_bounds__(256)
void cvt_f2b_kern(const float* __restrict__ in, unsigned short* __restrict__ out, int n) {
  int i = (blockIdx.x * blockDim.x + threadIdx.x) * 8;
  if (i >= n) return;
  float4 a = *(const float4*)(in + i);
  float4 b = *(const float4*)(in + i + 4);
  ushort4 o0; o0.x = f2b(a.x); o0.y = f2b(a.y); o0.z = f2b(a.z); o0.w = f2b(a.w);
  ushort4 o1; o1.x = f2b(b.x); o1.y = f2b(b.y); o1.z = f2b(b.z); o1.w = f2b(b.w);
  *(ushort4*)(out + i)     = o0;
  *(ushort4*)(out + i + 4) = o1;
}

// 4 weight matrices in one launch (blockIdx.y selects the matrix)
__global__ __launch_bounds__(256)
void cvt_f2b4_kern(const float* __restrict__ s0, const float* __restrict__ s1,
                   const float* __restrict__ s2, const float* __restrict__ s3,
                   unsigned short* __restrict__ d0, unsigned short* __restrict__ d1,
                   unsigned short* __restrict__ d2, unsigned short* __restrict__ d3,
                   int n) {
  const float* s; unsigned short* d;
  switch (blockIdx.y) {
    case 0: s = s0; d = d0; break;
    case 1: s = s1; d = d1; break;
    case 2: s = s2; d = d2; break;
    default: s = s3; d = d3; break;
  }
  int i = (blockIdx.x * blockDim.x + threadIdx.x) * 8;
  if (i >= n) return;
  float4 a = *(const float4*)(s + i);
  float4 b = *(const float4*)(s + i + 4);
  ushort4 o0; o0.x = f2b(a.x); o0.y = f2b(a.y); o0.z = f2b(a.z); o0.w = f2b(a.w);
  ushort4 o1; o1.x = f2b(b.x); o1.y = f2b(b.y); o1.z = f2b(b.z); o1.w = f2b(b.w);
  *(ushort4*)(d + i)     = o0;
  *(ushort4*)(d + i + 4) = o1;
}

// ---------------------------------------------------------------------------
// bf16 transpose: in [S][D] -> out [D][S], 64x64 tiles via LDS.
// ---------------------------------------------------------------------------
__global__ __launch_bounds__(256)
void transpose_bf16(const unsigned short* __restrict__ in, unsigned short* __restrict__ out) {
  __shared__ __align__(16) unsigned short Ts[64][72];
  const int d0 = blockIdx.x * 64, s0 = blockIdx.y * 64;
  const int r = threadIdx.x >> 2, q = threadIdx.x & 3;
#pragma unroll
  for (int hh = 0; hh < 2; ++hh) {
    const int c8 = q + hh * 4;
    us8 v = *(const us8*)(in + (size_t)(s0 + r) * DMODEL + d0 + c8 * 8);
    *(us8*)(&Ts[r][c8 * 8]) = v;
  }
  __syncthreads();
#pragma unroll
  for (int hh = 0; hh < 2; ++hh) {
    const int sq = q + hh * 4;
    __align__(16) unsigned short tmp[8];
#pragma unroll
    for (int j = 0; j < 8; ++j) tmp[j] = Ts[sq * 8 + j][r];
    *(us8*)(out + (size_t)(d0 + r) * S_LEN + s0 + sq * 8) = *(us8*)tmp;
  }
}

// ---------------------------------------------------------------------------
// LDS-staged GEMM body. R30: staging chunk split c = sq*2+p so each write
// instruction spreads across all 8 slots / 32 banks (was sq+4p: half range
// -> 2-way write conflicts).
// ---------------------------------------------------------------------------
template<int OUT_MODE>
__device__ __forceinline__
void gemm_body(const unsigned short* __restrict__ A, const unsigned short* __restrict__ B,
               const float* __restrict__ bias, void* __restrict__ Cout,
               int M, int N, int K, float scale, int bx, int by,
               unsigned short* As, unsigned short* Bs) {
  const int l  = threadIdx.x & 63;
  const int w  = threadIdx.x >> 6;
  const int wm = (w >> 1) * 32, wn = (w & 1) * 32;
  const int m0 = by * 64;
  const int n0 = bx * 64;
  const int lr = l & 15, lg = l >> 4;
  const int sr = threadIdx.x >> 2, sq = threadIdx.x & 3;

  f32x4 acc[2][2] = {};
  us8 areg[2], breg[2];

#pragma unroll
  for (int p = 0; p < 2; ++p) {
    const int c = sq * 2 + p;
    areg[p] = *(const us8*)(A + (size_t)(m0 + sr) * K + c * 8);
    breg[p] = *(const us8*)(B + (size_t)(n0 + sr) * K + c * 8);
  }
#pragma unroll
  for (int p = 0; p < 2; ++p) {
    const int c = sq * 2 + p;
    const int slot = ((c ^ (sr & 7)) * 8);
    *(us8*)(&As[sr * 64 + slot]) = areg[p];
    *(us8*)(&Bs[sr * 64 + slot]) = breg[p];
  }
  __syncthreads();

  const int nsteps = K / 64;  // 12
  for (int t = 0; t < nsteps; ++t) {
    const bool more = (t + 1 < nsteps);
    if (more) {
      const int kn = (t + 1) * 64;
#pragma unroll
      for (int p = 0; p < 2; ++p) {
        const int c = sq * 2 + p;
        areg[p] = *(const us8*)(A + (size_t)(m0 + sr) * K + kn + c * 8);
        breg[p] = *(const us8*)(B + (size_t)(n0 + sr) * K + kn + c * 8);
      }
    }
#pragma unroll
    for (int kc = 0; kc < 2; ++kc) {
      const int cr = kc * 4 + lg;
      bf16x8 af[2], bfr[2];
#pragma unroll
      for (int mi = 0; mi < 2; ++mi) {
        const int row = wm + mi * 16 + lr;
        af[mi] = *(const bf16x8*)(&As[row * 64 + ((cr ^ (row & 7)) * 8)]);
      }
#pragma unroll
      for (int ni = 0; ni < 2; ++ni) {
        const int row = wn + ni * 16 + lr;
        bfr[ni] = *(const bf16x8*)(&Bs[row * 64 + ((cr ^ (row & 7)) * 8)]);
      }
#pragma unroll
      for (int mi = 0; mi < 2; ++mi)
#pragma unroll
        for (int ni = 0; ni < 2; ++ni)
          acc[mi][ni] = __builtin_amdgcn_mfma_f32_16x16x32_bf16(af[mi], bfr[ni], acc[mi][ni], 0, 0, 0);
    }
    __syncthreads();
    if (more) {
#pragma unroll
      for (int p = 0; p < 2; ++p) {
        const int c = sq * 2 + p;
        const int slot = ((c ^ (sr & 7)) * 8);
        *(us8*)(&As[sr * 64 + slot]) = areg[p];
        *(us8*)(&Bs[sr * 64 + slot]) = breg[p];
      }
      __syncthreads();
    }
  }

  const int orow = (l >> 4) * 4;
#pragma unroll
  for (int mi = 0; mi < 2; ++mi)
#pragma unroll
    for (int ni = 0; ni < 2; ++ni) {
      const int col = n0 + wn + ni * 16 + lr;
      float bb = (OUT_MODE == 1) ? bias[col] : 0.f;
#pragma unroll
      for (int r = 0; r < 4; ++r) {
        const int row = m0 + wm + mi * 16 + orow + r;
        float v = acc[mi][ni][r] * scale;
        if (OUT_MODE == 0)
          ((unsigned short*)Cout)[(size_t)row * N + col] = f2b(v);
        else
          ((float*)Cout)[(size_t)row * N + col] = v + bb;
      }
    }
}

// Fused QKV projection. Q scale = 0.125 * log2(e): softmax runs in exp2 domain.
__global__ __launch_bounds__(256)
void gemm_qkv_lds(const unsigned short* __restrict__ X,
                  const unsigned short* __restrict__ Wq, const unsigned short* __restrict__ Wk,
                  const unsigned short* __restrict__ Wv,
                  unsigned short* __restrict__ Qh, unsigned short* __restrict__ Kh,
                  unsigned short* __restrict__ Vh) {
  __shared__ __align__(16) unsigned short As[64 * 64];
  __shared__ __align__(16) unsigned short Bs[64 * 64];
  const unsigned short* B; unsigned short* C; float scale;
  switch (blockIdx.z) {
    case 0:  B = Wq; C = Qh; scale = 0.125f * 1.4426950408889634f; break;
    case 1:  B = Wk; C = Kh; scale = 1.0f;   break;
    default: B = Wv; C = Vh; scale = 1.0f;   break;
  }
  gemm_body<0>(X, B, nullptr, C, S_LEN, DMODEL, DMODEL, scale,
               blockIdx.x, blockIdx.y, As, Bs);
}

// Single GEMM (final projection, fp32 out + bias)
__global__ __launch_bounds__(256)
void gemm_lds_f32(const unsigned short* __restrict__ A, const unsigned short* __restrict__ B,
                  const float* __restrict__ bias, float* __restrict__ C) {
  __shared__ __align__(16) unsigned short As[64 * 64];
  __shared__ __align__(16) unsigned short Bs[64 * 64];
  gemm_body<1>(A, B, bias, C, S_LEN, DMODEL, DMODEL, 1.0f,
               blockIdx.x, blockIdx.y, As, Bs);
}

// ---------------------------------------------------------------------------
// Flash-style causal attention (R28 structure: 4 waves, QBLK=64, KVBLK=128,
// snake ordering, register prefetch). R30:
//  - staging chunk split qw = sq*2+p (bank-conflict fix)
//  - exp2-domain softmax (log2e folded into Q scale; v_exp_f32 direct)
//  - defer-max (THR=8): skip alpha/rescale when max growth is small
// ---------------------------------------------------------------------------
__global__ __launch_bounds__(256, 3)
void attn_fwd_mfma(const unsigned short* __restrict__ Q, const unsigned short* __restrict__ K,
                   const unsigned short* __restrict__ Vt, unsigned short* __restrict__ O) {
  __shared__ __align__(16) unsigned short Ks[2][64 * 64];
  __shared__ __align__(16) unsigned short Vs[2][64 * 64];
  __shared__ __align__(16) unsigned short Ps[4][2 * 16 * 64];

  const int item = blockIdx.x;
  int s;
  if (item < 256)      s = item;
  else if (item < 512) s = 767 - item;
  else                 s = item;
  const int qt = 63 - s / NHEAD;
  const int h  = s % NHEAD;
  const int q0 = qt * 64;
  const int tid = threadIdx.x;
  const int w = tid >> 6, l = tid & 63;
  const int lr = l & 15, lg = l >> 4;
  const int sr = tid >> 2, sq = tid & 3;

  bf16x8 qf[2];
#pragma unroll
  for (int kc = 0; kc < 2; ++kc)
    qf[kc] = *(const bf16x8*)(Q + (size_t)(q0 + w * 16 + lr) * DMODEL + h * HDIM + kc * 32 + lg * 8);

  f32x4 o_acc[4] = {};
  float m_i[4], l_i[4];
#pragma unroll
  for (int r = 0; r < 4; ++r) { m_i[r] = -1e30f; l_i[r] = 0.f; }

  const int nt2    = (qt + 2) >> 1;
  const int ntFull = (64 * qt >= 127) ? ((64 * qt - 127) / 128 + 1) : 0;

  us8 kreg[2][2], vreg[2][2];

#pragma unroll
  for (int hh = 0; hh < 2; ++hh)
#pragma unroll
    for (int p = 0; p < 2; ++p) {
      const int qw = sq * 2 + p;
      kreg[hh][p] = *(const us8*)(K  + (size_t)(hh * 64 + sr) * DMODEL + h * HDIM + qw * 8);
      vreg[hh][p] = *(const us8*)(Vt + (size_t)(h * HDIM + sr) * S_LEN + hh * 64 + qw * 8);
    }
#pragma unroll
  for (int hh = 0; hh < 2; ++hh)
#pragma unroll
    for (int p = 0; p < 2; ++p) {
      const int qw = sq * 2 + p;
      const int sw = (qw * 8) ^ ((sr & 7) * 8);
      *(us8*)(&Ks[hh][sr * 64 + sw]) = kreg[hh][p];
      *(us8*)(&Vs[hh][sr * 64 + sw]) = vreg[hh][p];
    }
  __syncthreads();

  for (int t = 0; t < nt2; ++t) {
    const int k0 = t * 128;
    const bool more = (t + 1 < nt2);
    const bool need_mask = (t >= ntFull);

    if (more) {
      const int k0n = k0 + 128;
#pragma unroll
      for (int hh = 0; hh < 2; ++hh)
#pragma unroll
        for (int p = 0; p < 2; ++p) {
          const int qw = sq * 2 + p;
          kreg[hh][p] = *(const us8*)(K  + (size_t)(k0n + hh * 64 + sr) * DMODEL + h * HDIM + qw * 8);
          vreg[hh][p] = *(const us8*)(Vt + (size_t)(h * HDIM + sr) * S_LEN + k0n + hh * 64 + qw * 8);
        }
    }

    f32x4 sacc[2][4] = {};
#pragma unroll
    for (int hh = 0; hh < 2; ++hh)
#pragma unroll
      for (int kc = 0; kc < 2; ++kc)
#pragma unroll
        for (int cb = 0; cb < 4; ++cb) {
          const int kv = cb * 16 + lr;
          bf16x8 kf = *(const bf16x8*)(&Ks[hh][kv * 64 + ((kc * 32 + lg * 8) ^ ((kv & 7) * 8))]);
          sacc[hh][cb] = __builtin_amdgcn_mfma_f32_16x16x32_bf16(qf[kc], kf, sacc[hh][cb], 0, 0, 0);
        }

    // ---- online softmax, exp2 domain, defer-max ----
    float sv[4][8], pm[4];
#pragma unroll
    for (int r = 0; r < 4; ++r) {
      const int qg = q0 + w * 16 + lg * 4 + r;
#pragma unroll
      for (int hh = 0; hh < 2; ++hh)
#pragma unroll
        for (int cb = 0; cb < 4; ++cb)
          sv[r][hh * 4 + cb] = sacc[hh][cb][r];
      if (need_mask) {
#pragma unroll
        for (int hh = 0; hh < 2; ++hh)
#pragma unroll
          for (int cb = 0; cb < 4; ++cb) {
            const int kg = k0 + hh * 64 + cb * 16 + lr;
            if (kg > qg) sv[r][hh * 4 + cb] = -1e30f;
          }
      }
      float mt = fmaxf(fmaxf(fmaxf(sv[r][0], sv[r][1]), fmaxf(sv[r][2], sv[r][3])),
                       fmaxf(fmaxf(sv[r][4], sv[r][5]), fmaxf(sv[r][6], sv[r][7])));
      pm[r] = dpp_max16(mt);
    }

    const int ok = (pm[0] <= m_i[0] + 8.f) && (pm[1] <= m_i[1] + 8.f) &&
                   (pm[2] <= m_i[2] + 8.f) && (pm[3] <= m_i[3] + 8.f);
    if (!__all(ok)) {
#pragma unroll
      for (int r = 0; r < 4; ++r) {
        const float mnew = fmaxf(m_i[r], pm[r]);
        const float alpha = __builtin_amdgcn_exp2f(m_i[r] - mnew);
        m_i[r] = mnew;
        l_i[r] *= alpha;
#pragma unroll
        for (int db = 0; db < 4; ++db) o_acc[db][r] *= alpha;
      }
    }

    float p[4][8];
#pragma unroll
    for (int r = 0; r < 4; ++r) {
      float rs = 0.f;
#pragma unroll
      for (int e = 0; e < 8; ++e) { p[r][e] = __builtin_amdgcn_exp2f(sv[r][e] - m_i[r]); rs += p[r][e]; }
      rs = dpp_sum16(rs);
      l_i[r] += rs;
    }

#pragma unroll
    for (int r = 0; r < 4; ++r) {
      const int qloc = lg * 4 + r;
#pragma unroll
      for (int hh = 0; hh < 2; ++hh)
#pragma unroll
        for (int cb = 0; cb < 4; ++cb) {
          const int kvl = cb * 16 + lr;
          Ps[w][hh * 1024 + qloc * 64 + (kvl ^ ((qloc & 7) * 8))] = f2b(p[r][hh * 4 + cb]);
        }
    }

#pragma unroll
    for (int hh = 0; hh < 2; ++hh)
#pragma unroll
      for (int kc = 0; kc < 2; ++kc) {
        bf16x8 pf = *(const bf16x8*)(&Ps[w][hh * 1024 + lr * 64 + ((kc * 32 + lg * 8) ^ ((lr & 7) * 8))]);
#pragma unroll
        for (int db = 0; db < 4; ++db) {
          const int d = db * 16 + lr;
          bf16x8 vf = *(const bf16x8*)(&Vs[hh][d * 64 + ((kc * 32 + lg * 8) ^ ((d & 7) * 8))]);
          o_acc[db] = __builtin_amdgcn_mfma_f32_16x16x32_bf16(pf, vf, o_acc[db], 0, 0, 0);
        }
      }

    __syncthreads();
    if (more) {
#pragma unroll
      for (int hh = 0; hh < 2; ++hh)
#pragma unroll
        for (int p = 0; p < 2; ++p) {
          const int qw = sq * 2 + p;
          const int sw = (qw * 8) ^ ((sr & 7) * 8);
          *(us8*)(&Ks[hh][sr * 64 + sw]) = kreg[hh][p];
          *(us8*)(&Vs[hh][sr * 64 + sw]) = vreg[hh][p];
        }
      __syncthreads();
    }
  }

#pragma unroll
  for (int r = 0; r < 4; ++r) {
    const float inv = 1.f / l_i[r];
    const int row = q0 + w * 16 + lg * 4 + r;
#pragma unroll
    for (int db = 0; db < 4; ++db)
      O[(size_t)row * DMODEL + h * HDIM + db * 16 + lr] = f2b(o_acc[db][r] * inv);
  }
}

// ---------------------------------------------------------------------------
extern "C" void kernel_launch(void* const* d_in, const int* in_sizes, int n_in,
                              void* d_out, int out_size, void* d_ws, size_t ws_size,
                              hipStream_t stream) {
  const float* x  = (const float*)d_in[0];
  const float* Wq = (const float*)d_in[1];
  const float* Wk = (const float*)d_in[2];
  const float* Wv = (const float*)d_in[3];
  const float* Wo = (const float*)d_in[4];
  const float* bo = (const float*)d_in[5];
  float* out = (float*)d_out;

  const size_t SD = (size_t)S_LEN * DMODEL;   // 3,145,728
  const size_t DD = (size_t)DMODEL * DMODEL;  //   589,824

  unsigned short* xh   = (unsigned short*)d_ws;
  unsigned short* Wqh  = xh   + SD;
  unsigned short* Wkh  = Wqh  + DD;
  unsigned short* Wvh  = Wkh  + DD;
  unsigned short* Woh  = Wvh  + DD;
  unsigned short* Qh   = Woh  + DD;
  unsigned short* Kh   = Qh   + SD;
  unsigned short* Vh   = Kh   + SD;
  unsigned short* Vth  = Vh   + SD;
  unsigned short* ctxh = Vth  + SD;

  const dim3 blk(256);

  cvt_f2b_kern<<<dim3((int)(SD / 8 / 256)), blk, 0, stream>>>(x, xh, (int)SD);
  cvt_f2b4_kern<<<dim3((int)(DD / 8 / 256), 4), blk, 0, stream>>>(
      Wq, Wk, Wv, Wo, Wqh, Wkh, Wvh, Woh, (int)DD);

  gemm_qkv_lds<<<dim3(DMODEL / 64, S_LEN / 64, 3), blk, 0, stream>>>(
      xh, Wqh, Wkh, Wvh, Qh, Kh, Vh);

  transpose_bf16<<<dim3(DMODEL / 64, S_LEN / 64), blk, 0, stream>>>(Vh, Vth);

  attn_fwd_mfma<<<dim3(S_LEN / 64 * NHEAD), blk, 0, stream>>>(Qh, Kh, Vth, ctxh);

  gemm_lds_f32<<<dim3(DMODEL / 64, S_LEN / 64), blk, 0, stream>>>(ctxh, Woh, bo, out);
}